// Round 7
// baseline (140.785 us; speedup 1.0000x reference)
//
#include <hip/hip_runtime.h>
#include <math.h>

#define NROWS 32768
#define CDIM  512
#define G_    2
#define V_    320
#define NCOLS 640
#define DCODE 128
#define NSLOT 32

typedef short bf16x8 __attribute__((ext_vector_type(8)));
typedef float f32x4  __attribute__((ext_vector_type(4)));

__device__ __forceinline__ short f2bf(float f) {
    union { float f; unsigned u; } v; v.f = f;
    unsigned r = v.u + 0x7FFFu + ((v.u >> 16) & 1u);   // RTNE
    return (short)(r >> 16);
}

// W [512][640] f32 -> wpk fragment-packed bf16 (640 KB).
// frag index = ((g*16+ts)*20 + tt16)*64 + kq*16 + l15, elem e:
//   value = bf16(w[ts*32 + kq*8 + e][g*320 + tt16*16 + l15])
// => a wave's B-fragment load is wpk + frag_base*8 + lane*8 shorts: one coalesced 1-KB line.
__global__ __launch_bounds__(256) void wprep(const float* __restrict__ w,
                                             short* __restrict__ wpk) {
    int gid = blockIdx.x * 256 + threadIdx.x;       // 40960 fragments
    int l15 = gid & 15, kq = (gid >> 4) & 3;
    int rem = gid >> 6;
    int tt16 = rem % 20; rem /= 20;
    int ts = rem & 15, g = rem >> 4;
    int n  = g * V_ + tt16 * 16 + l15;
    int k0 = ts * 32 + kq * 8;
    bf16x8 o;
    #pragma unroll
    for (int e = 0; e < 8; ++e) o[e] = f2bf(w[(size_t)(k0 + e) * NCOLS + n]);
    *(bf16x8*)&wpk[(size_t)gid * 8] = o;
}

// Block = 16 rows x one group, 128 threads = 2 waves (ch = col half).
// Wave tile 16 rows x 160 cols, MFMA 16x16x32 bf16, acc = 10 x f32x4.
// No LDS tiles, no K-loop barriers: A direct from hidden (+cvt), B from L2-resident wpk.
__global__ __launch_bounds__(128, 4) void gvq_gemm(
    const float* __restrict__ hidden,    // [32768][512] f32
    const float* __restrict__ gumbel_u,  // [65536][320] f32
    const short* __restrict__ wpk,       // fragment-packed bf16
    const float* __restrict__ bias,      // [640]
    const float* __restrict__ cv,        // [640][128]
    float* __restrict__ out,             // [32768][256] + perp scalar
    float* __restrict__ gavg)            // [NSLOT][640]
{
    __shared__ float s_psum[2][16];
    __shared__ float s_bestv[2][16];
    __shared__ int   s_besti[2][16];

    const int t    = threadIdx.x;
    const int ch   = t >> 6;
    const int lane = t & 63;
    const int l15  = lane & 15;
    const int kq   = lane >> 4;           // k-chunk of 8 within K=32
    const int rb   = blockIdx.x;
    const int g    = blockIdx.y;
    const int m0   = rb * 16;

    const float* arow  = hidden + (size_t)(m0 + l15) * CDIM + kq * 8;
    const short* wbase = wpk + ((size_t)(g * 16) * 20 + ch * 10) * 512 + (size_t)lane * 8;
    // per ts: +ts*10240 shorts; per tt within half: +tt*512

    f32x4 acc[10];
    #pragma unroll
    for (int tt = 0; tt < 10; ++tt)
        #pragma unroll
        for (int r = 0; r < 4; ++r) acc[tt][r] = 0.f;

    // prologue: A(ts=0) + B first-half(ts=0)
    float4 a0lo = *(const float4*)(arow);
    float4 a0hi = *(const float4*)(arow + 4);
    bf16x8 b0[5];
    #pragma unroll
    for (int j = 0; j < 5; ++j) b0[j] = *(const bf16x8*)(wbase + j * 512);

    #pragma unroll
    for (int ts = 0; ts < 16; ++ts) {
        const short* wts = wbase + ts * 10240;
        bf16x8 b1[5];
        #pragma unroll
        for (int j = 0; j < 5; ++j) b1[j] = *(const bf16x8*)(wts + (5 + j) * 512);
        float4 a1lo, a1hi;
        if (ts < 15) {                                   // prefetch A for ts+1
            a1lo = *(const float4*)(arow + (ts + 1) * 32);
            a1hi = *(const float4*)(arow + (ts + 1) * 32 + 4);
        }
        bf16x8 af;
        af[0]=f2bf(a0lo.x); af[1]=f2bf(a0lo.y); af[2]=f2bf(a0lo.z); af[3]=f2bf(a0lo.w);
        af[4]=f2bf(a0hi.x); af[5]=f2bf(a0hi.y); af[6]=f2bf(a0hi.z); af[7]=f2bf(a0hi.w);
        #pragma unroll
        for (int j = 0; j < 5; ++j)
            acc[j] = __builtin_amdgcn_mfma_f32_16x16x32_bf16(af, b0[j], acc[j], 0, 0, 0);
        if (ts < 15) {                                   // prefetch B first-half for ts+1
            #pragma unroll
            for (int j = 0; j < 5; ++j)
                b0[j] = *(const bf16x8*)(wts + 10240 + j * 512);
        }
        #pragma unroll
        for (int j = 0; j < 5; ++j)
            acc[5 + j] = __builtin_amdgcn_mfma_f32_16x16x32_bf16(af, b1[j], acc[5 + j], 0, 0, 0);
        a0lo = a1lo; a0hi = a1hi;
    }

    // ---- epilogue ----
    // C/D: col = g*320 + ch*160 + tt*16 + l15, local row rl = kq*4 + r
    float bvv[10];
    #pragma unroll
    for (int tt = 0; tt < 10; ++tt) bvv[tt] = bias[g * V_ + ch * 160 + tt * 16 + l15];

    {   // exp(z) direct + row sums + 1-log gumbel ratio argmax, u-loads pipelined
        float ub[10], un[10];
        {
            const float* up0 = gumbel_u + ((size_t)(m0 + kq * 4) * G_ + g) * V_ + ch * 160 + l15;
            #pragma unroll
            for (int tt = 0; tt < 10; ++tt) ub[tt] = up0[tt * 16];
        }
        #pragma unroll
        for (int r = 0; r < 4; ++r) {
            const int rl = kq * 4 + r;
            if (r < 3) {
                const float* upn = gumbel_u + ((size_t)(m0 + rl + 1) * G_ + g) * V_ + ch * 160 + l15;
                #pragma unroll
                for (int tt = 0; tt < 10; ++tt) un[tt] = upn[tt * 16];
            }
            float s = 0.f, best = -1e30f; int bi = 0;
            #pragma unroll
            for (int tt = 0; tt < 10; ++tt) {
                float z = fminf(acc[tt][r] + bvv[tt], 60.f);
                float e = __expf(z);
                acc[tt][r] = e;                              // keep numerator for cp pass
                s += e;
                float w = -__logf(ub[tt] + 1e-10f) + 1e-10f;
                float ratio = e * __builtin_amdgcn_rcpf(w);  // argmax(z+gumbel) == argmax e/w
                if (ratio > best) { best = ratio; bi = ch * 160 + tt * 16 + l15; }
            }
            #pragma unroll
            for (int o = 1; o <= 8; o <<= 1) {               // 16-lane group reduce
                s += __shfl_xor(s, o);
                float ov = __shfl_xor(best, o);
                int   oi = __shfl_xor(bi, o);
                if (ov > best || (ov == best && oi < bi)) { best = ov; bi = oi; }
            }
            if (l15 == 0) {
                s_psum[ch][rl]  = s;
                s_bestv[ch][rl] = best;
                s_besti[ch][rl] = bi;
            }
            #pragma unroll
            for (int tt = 0; tt < 10; ++tt) ub[tt] = un[tt];
        }
    }
    __syncthreads();

    // probability accumulation -> fold kq groups -> sliced global atomics
    float cp[10];
    #pragma unroll
    for (int tt = 0; tt < 10; ++tt) cp[tt] = 0.f;
    #pragma unroll
    for (int r = 0; r < 4; ++r) {
        const int rl = kq * 4 + r;
        const float inv = 1.f / (s_psum[0][rl] + s_psum[1][rl]);
        #pragma unroll
        for (int tt = 0; tt < 10; ++tt) cp[tt] += acc[tt][r] * inv;
    }
    #pragma unroll
    for (int tt = 0; tt < 10; ++tt) {
        cp[tt] += __shfl_xor(cp[tt], 16);
        cp[tt] += __shfl_xor(cp[tt], 32);
    }
    float* gslot = gavg + (size_t)(rb & (NSLOT - 1)) * NCOLS;
    if (kq == 0) {
        #pragma unroll
        for (int tt = 0; tt < 10; ++tt)
            atomicAdd(&gslot[g * V_ + ch * 160 + tt * 16 + l15], cp[tt]);
    }

    // final argmax across col-halves + codevector gather + write (8 rows per wave)
    #pragma unroll
    for (int i = 0; i < 8; ++i) {
        const int R = ch * 8 + i;
        float v0 = s_bestv[0][R], v1 = s_bestv[1][R];
        int   i0 = s_besti[0][R], i1 = s_besti[1][R];
        int bidx = (v1 > v0) ? i1 : i0;     // tie -> ch0 (smaller index)
        float2 cvv = *(const float2*)(cv + ((size_t)g * V_ + bidx) * DCODE + lane * 2);
        *(float2*)(out + (size_t)(m0 + R) * (G_ * DCODE) + g * DCODE + lane * 2) = cvv;
    }
}

__global__ __launch_bounds__(64) void gvq_perp(const float* __restrict__ gavg,
                                               float* __restrict__ out, int nslot)
{
    const int lane = threadIdx.x;
    float s0 = 0.f, s1 = 0.f;
    for (int v = lane; v < V_; v += 64) {
        float p0 = 0.f, p1 = 0.f;
        for (int s = 0; s < nslot; ++s) {
            p0 += gavg[(size_t)s * NCOLS + v];
            p1 += gavg[(size_t)s * NCOLS + V_ + v];
        }
        p0 *= (1.f / NROWS); p1 *= (1.f / NROWS);
        s0 += p0 * logf(p0 + 1e-7f);
        s1 += p1 * logf(p1 + 1e-7f);
    }
    #pragma unroll
    for (int o = 32; o >= 1; o >>= 1) {
        s0 += __shfl_xor(s0, o);
        s1 += __shfl_xor(s1, o);
    }
    if (lane == 0)
        out[(size_t)NROWS * (G_ * DCODE)] = expf(-s0) + expf(-s1);
}

extern "C" void kernel_launch(void* const* d_in, const int* in_sizes, int n_in,
                              void* d_out, int out_size, void* d_ws, size_t ws_size,
                              hipStream_t stream)
{
    const float* hidden = (const float*)d_in[0];
    const float* gu     = (const float*)d_in[1];
    const float* w      = (const float*)d_in[2];
    const float* b      = (const float*)d_in[3];
    const float* cv     = (const float*)d_in[4];
    float* out  = (float*)d_out;
    float* gavg = (float*)d_ws;                       // [NSLOT][640] f32 = 80 KB
    short* wpk  = (short*)((char*)d_ws + 81920);      // 640 KB fragment-packed W

    hipMemsetAsync(d_ws, 0, NSLOT * NCOLS * sizeof(float), stream);
    wprep<<<160, 256, 0, stream>>>(w, wpk);
    gvq_gemm<<<dim3(NROWS / 16, G_), 128, 0, stream>>>(hidden, gu, wpk, b, cv, out, gavg);
    gvq_perp<<<1, 64, 0, stream>>>(gavg, out, NSLOT);
}

// Round 8
// 139.602 us; speedup vs baseline: 1.0085x; 1.0085x over previous
//
#include <hip/hip_runtime.h>
#include <math.h>

#define NROWS 32768
#define CDIM  512
#define G_    2
#define V_    320
#define NCOLS 640
#define DCODE 128
#define NSLOT 32

typedef short bf16x8 __attribute__((ext_vector_type(8)));
typedef float f32x4  __attribute__((ext_vector_type(4)));

__device__ __forceinline__ short f2bf(float f) {
    union { float f; unsigned u; } v; v.f = f;
    unsigned r = v.u + 0x7FFFu + ((v.u >> 16) & 1u);   // RTNE
    return (short)(r >> 16);
}

// W [512][640] f32 -> wpk fragment-packed bf16 (640 KB).
// frag index = ((g*16+ts)*20 + tt16)*64 + kq*16 + l15, elem e:
//   value = bf16(w[ts*32 + kq*8 + e][g*320 + tt16*16 + l15])
__global__ __launch_bounds__(256) void wprep(const float* __restrict__ w,
                                             short* __restrict__ wpk) {
    int gid = blockIdx.x * 256 + threadIdx.x;       // 40960 fragments
    int l15 = gid & 15, kq = (gid >> 4) & 3;
    int rem = gid >> 6;
    int tt16 = rem % 20; rem /= 20;
    int ts = rem & 15, g = rem >> 4;
    int n  = g * V_ + tt16 * 16 + l15;
    int k0 = ts * 32 + kq * 8;
    bf16x8 o;
    #pragma unroll
    for (int e = 0; e < 8; ++e) o[e] = f2bf(w[(size_t)(k0 + e) * NCOLS + n]);
    *(bf16x8*)&wpk[(size_t)gid * 8] = o;
}

// Block = 32 rows x one group, 128 threads = 2 waves (ch = col half).
// Wave tile 32 rows x 160 cols (2 row-tiles share B), MFMA 16x16x32, acc = 2x10xf32x4.
__global__ __launch_bounds__(128, 3) void gvq_gemm(
    const float* __restrict__ hidden,    // [32768][512] f32
    const float* __restrict__ gumbel_u,  // [65536][320] f32
    const short* __restrict__ wpk,       // fragment-packed bf16
    const float* __restrict__ bias,      // [640]
    const float* __restrict__ cv,        // [640][128]
    float* __restrict__ out,             // [32768][256] + perp scalar
    float* __restrict__ gavg)            // [NSLOT][640]
{
    __shared__ float s_psum[2][32];
    __shared__ float s_bestv[2][32];
    __shared__ int   s_besti[2][32];

    const int t    = threadIdx.x;
    const int ch   = t >> 6;
    const int lane = t & 63;
    const int l15  = lane & 15;
    const int kq   = lane >> 4;           // k-chunk of 8 within K=32
    const int rb   = blockIdx.x;
    const int g    = blockIdx.y;
    const int m0   = rb * 32;

    const float* arow0 = hidden + (size_t)(m0 + l15) * CDIM + kq * 8;
    const float* arow1 = hidden + (size_t)(m0 + 16 + l15) * CDIM + kq * 8;
    const short* wbase = wpk + ((size_t)(g * 16) * 20 + ch * 10) * 512 + (size_t)lane * 8;

    f32x4 acc[2][10];
    #pragma unroll
    for (int ti = 0; ti < 2; ++ti)
        #pragma unroll
        for (int tt = 0; tt < 10; ++tt)
            #pragma unroll
            for (int r = 0; r < 4; ++r) acc[ti][tt][r] = 0.f;

    // prologue: A(ts=0) both row-tiles + B first-half(ts=0)
    float4 a0lo = *(const float4*)(arow0);
    float4 a0hi = *(const float4*)(arow0 + 4);
    float4 a2lo = *(const float4*)(arow1);
    float4 a2hi = *(const float4*)(arow1 + 4);
    bf16x8 b0[5];
    #pragma unroll
    for (int j = 0; j < 5; ++j) b0[j] = *(const bf16x8*)(wbase + j * 512);

    #pragma unroll
    for (int ts = 0; ts < 16; ++ts) {
        const short* wts = wbase + ts * 10240;
        bf16x8 b1[5];
        #pragma unroll
        for (int j = 0; j < 5; ++j) b1[j] = *(const bf16x8*)(wts + (5 + j) * 512);
        float4 n0lo, n0hi, n2lo, n2hi;
        if (ts < 15) {                                   // prefetch A for ts+1
            n0lo = *(const float4*)(arow0 + (ts + 1) * 32);
            n0hi = *(const float4*)(arow0 + (ts + 1) * 32 + 4);
            n2lo = *(const float4*)(arow1 + (ts + 1) * 32);
            n2hi = *(const float4*)(arow1 + (ts + 1) * 32 + 4);
        }
        bf16x8 af0, af1;
        af0[0]=f2bf(a0lo.x); af0[1]=f2bf(a0lo.y); af0[2]=f2bf(a0lo.z); af0[3]=f2bf(a0lo.w);
        af0[4]=f2bf(a0hi.x); af0[5]=f2bf(a0hi.y); af0[6]=f2bf(a0hi.z); af0[7]=f2bf(a0hi.w);
        af1[0]=f2bf(a2lo.x); af1[1]=f2bf(a2lo.y); af1[2]=f2bf(a2lo.z); af1[3]=f2bf(a2lo.w);
        af1[4]=f2bf(a2hi.x); af1[5]=f2bf(a2hi.y); af1[6]=f2bf(a2hi.z); af1[7]=f2bf(a2hi.w);
        #pragma unroll
        for (int j = 0; j < 5; ++j) {
            acc[0][j] = __builtin_amdgcn_mfma_f32_16x16x32_bf16(af0, b0[j], acc[0][j], 0, 0, 0);
            acc[1][j] = __builtin_amdgcn_mfma_f32_16x16x32_bf16(af1, b0[j], acc[1][j], 0, 0, 0);
        }
        if (ts < 15) {                                   // prefetch B first-half for ts+1
            #pragma unroll
            for (int j = 0; j < 5; ++j)
                b0[j] = *(const bf16x8*)(wts + 10240 + j * 512);
        }
        #pragma unroll
        for (int j = 0; j < 5; ++j) {
            acc[0][5 + j] = __builtin_amdgcn_mfma_f32_16x16x32_bf16(af0, b1[j], acc[0][5 + j], 0, 0, 0);
            acc[1][5 + j] = __builtin_amdgcn_mfma_f32_16x16x32_bf16(af1, b1[j], acc[1][5 + j], 0, 0, 0);
        }
        a0lo = n0lo; a0hi = n0hi; a2lo = n2lo; a2hi = n2hi;
    }

    // ---- epilogue ----
    // C/D: col = g*320 + ch*160 + tt*16 + l15, local row rl = ti*16 + kq*4 + r
    float bvv[10];
    #pragma unroll
    for (int tt = 0; tt < 10; ++tt) bvv[tt] = bias[g * V_ + ch * 160 + tt * 16 + l15];

    float cp[10];
    #pragma unroll
    for (int tt = 0; tt < 10; ++tt) cp[tt] = 0.f;

    {   // exp(z) direct + row sums + 1-log gumbel ratio argmax; u-loads pipelined
        float ub[10], un[10];
        {
            const float* up0 = gumbel_u + ((size_t)(m0 + kq * 4) * G_ + g) * V_ + ch * 160 + l15;
            #pragma unroll
            for (int tt = 0; tt < 10; ++tt) ub[tt] = up0[tt * 16];
        }
        #pragma unroll
        for (int rr = 0; rr < 8; ++rr) {
            const int ti = rr >> 2, r = rr & 3;
            const int rl = ti * 16 + kq * 4 + r;
            if (rr < 7) {
                const int rln = ((rr + 1) >> 2) * 16 + kq * 4 + ((rr + 1) & 3);
                const float* upn = gumbel_u + ((size_t)(m0 + rln) * G_ + g) * V_ + ch * 160 + l15;
                #pragma unroll
                for (int tt = 0; tt < 10; ++tt) un[tt] = upn[tt * 16];
            }
            float s = 0.f, best = -1e30f; int bi = 0;
            #pragma unroll
            for (int tt = 0; tt < 10; ++tt) {
                float z = fminf(acc[ti][tt][r] + bvv[tt], 60.f);
                float e = __expf(z);
                acc[ti][tt][r] = e;                          // keep numerator
                s += e;
                float w = -__logf(ub[tt] + 1e-10f) + 1e-10f;
                float ratio = e * __builtin_amdgcn_rcpf(w);  // argmax(z+gumbel) == argmax e/w
                if (ratio > best) { best = ratio; bi = ch * 160 + tt * 16 + l15; }
            }
            #pragma unroll
            for (int o = 1; o <= 8; o <<= 1) {               // 16-lane group reduce
                s += __shfl_xor(s, o);
                float ov = __shfl_xor(best, o);
                int   oi = __shfl_xor(bi, o);
                if (ov > best || (ov == best && oi < bi)) { best = ov; bi = oi; }
            }
            if (l15 == 0) {
                s_psum[ch][rl]  = s;
                s_bestv[ch][rl] = best;
                s_besti[ch][rl] = bi;
            }
            #pragma unroll
            for (int tt = 0; tt < 10; ++tt) ub[tt] = un[tt];
        }
    }
    __syncthreads();

    // probability accumulation (8 reg-rows) -> fold kq groups -> sliced global atomics
    #pragma unroll
    for (int rr = 0; rr < 8; ++rr) {
        const int ti = rr >> 2, r = rr & 3;
        const int rl = ti * 16 + kq * 4 + r;
        const float inv = 1.f / (s_psum[0][rl] + s_psum[1][rl]);
        #pragma unroll
        for (int tt = 0; tt < 10; ++tt) cp[tt] += acc[ti][tt][r] * inv;
    }
    #pragma unroll
    for (int tt = 0; tt < 10; ++tt) {
        cp[tt] += __shfl_xor(cp[tt], 16);
        cp[tt] += __shfl_xor(cp[tt], 32);
    }
    float* gslot = gavg + (size_t)(rb & (NSLOT - 1)) * NCOLS;
    if (kq == 0) {
        #pragma unroll
        for (int tt = 0; tt < 10; ++tt)
            atomicAdd(&gslot[g * V_ + ch * 160 + tt * 16 + l15], cp[tt]);
    }

    // final argmax across col-halves + codevector gather + write (16 rows per wave)
    #pragma unroll
    for (int i = 0; i < 16; ++i) {
        const int R = ch * 16 + i;
        float v0 = s_bestv[0][R], v1 = s_bestv[1][R];
        int   i0 = s_besti[0][R], i1 = s_besti[1][R];
        int bidx = (v1 > v0) ? i1 : i0;     // tie -> ch0 (smaller index)
        float2 cvv = *(const float2*)(cv + ((size_t)g * V_ + bidx) * DCODE + lane * 2);
        *(float2*)(out + (size_t)(m0 + R) * (G_ * DCODE) + g * DCODE + lane * 2) = cvv;
    }
}

__global__ __launch_bounds__(64) void gvq_perp(const float* __restrict__ gavg,
                                               float* __restrict__ out, int nslot)
{
    const int lane = threadIdx.x;
    float s0 = 0.f, s1 = 0.f;
    for (int v = lane; v < V_; v += 64) {
        float p0 = 0.f, p1 = 0.f;
        for (int s = 0; s < nslot; ++s) {
            p0 += gavg[(size_t)s * NCOLS + v];
            p1 += gavg[(size_t)s * NCOLS + V_ + v];
        }
        p0 *= (1.f / NROWS); p1 *= (1.f / NROWS);
        s0 += p0 * logf(p0 + 1e-7f);
        s1 += p1 * logf(p1 + 1e-7f);
    }
    #pragma unroll
    for (int o = 32; o >= 1; o >>= 1) {
        s0 += __shfl_xor(s0, o);
        s1 += __shfl_xor(s1, o);
    }
    if (lane == 0)
        out[(size_t)NROWS * (G_ * DCODE)] = expf(-s0) + expf(-s1);
}

extern "C" void kernel_launch(void* const* d_in, const int* in_sizes, int n_in,
                              void* d_out, int out_size, void* d_ws, size_t ws_size,
                              hipStream_t stream)
{
    const float* hidden = (const float*)d_in[0];
    const float* gu     = (const float*)d_in[1];
    const float* w      = (const float*)d_in[2];
    const float* b      = (const float*)d_in[3];
    const float* cv     = (const float*)d_in[4];
    float* out  = (float*)d_out;
    float* gavg = (float*)d_ws;                       // [NSLOT][640] f32 = 80 KB
    short* wpk  = (short*)((char*)d_ws + 81920);      // 640 KB fragment-packed W

    hipMemsetAsync(d_ws, 0, NSLOT * NCOLS * sizeof(float), stream);
    wprep<<<160, 256, 0, stream>>>(w, wpk);
    gvq_gemm<<<dim3(NROWS / 32, G_), 128, 0, stream>>>(hidden, gu, wpk, b, cv, out, gavg);
    gvq_perp<<<1, 64, 0, stream>>>(gavg, out, NSLOT);
}

// Round 9
// 128.892 us; speedup vs baseline: 1.0923x; 1.0831x over previous
//
#include <hip/hip_runtime.h>
#include <math.h>

#define NROWS 32768
#define CDIM  512
#define G_    2
#define V_    320
#define NCOLS 640
#define DCODE 128
#define NSLOT 32
#define CHUNK 520   // shorts per A-frag chunk (512 + 8 pad: de-conflict stage writes)

typedef short bf16x4 __attribute__((ext_vector_type(4)));
typedef short bf16x8 __attribute__((ext_vector_type(8)));
typedef float f32x4  __attribute__((ext_vector_type(4)));

__device__ __forceinline__ short f2bf(float f) {
    union { float f; unsigned u; } v; v.f = f;
    unsigned r = v.u + 0x7FFFu + ((v.u >> 16) & 1u);   // RTNE
    return (short)(r >> 16);
}

// W [512][640] f32 -> wpk fragment-packed bf16 (640 KB), frag = ((g*16+ts)*20+tt16)*64 + kq*16 + l15
__global__ __launch_bounds__(256) void wprep(const float* __restrict__ w,
                                             short* __restrict__ wpk) {
    int gid = blockIdx.x * 256 + threadIdx.x;       // 40960 fragments
    int l15 = gid & 15, kq = (gid >> 4) & 3;
    int rem = gid >> 6;
    int tt16 = rem % 20; rem /= 20;
    int ts = rem & 15, g = rem >> 4;
    int n  = g * V_ + tt16 * 16 + l15;
    int k0 = ts * 32 + kq * 8;
    bf16x8 o;
    #pragma unroll
    for (int e = 0; e < 8; ++e) o[e] = f2bf(w[(size_t)(k0 + e) * NCOLS + n]);
    *(bf16x8*)&wpk[(size_t)gid * 8] = o;
}

// Block = 32 rows x 640 cols (both groups), 512 thr = 8 waves: rq = w>>2, cq = w&3, g = cq>>1, ch = cq&1.
// A: whole-K fragment-major LDS tile staged once (bf16). B: fragment-streamed from L2 wpk.
// K-loop: no barriers. MFMA 16x16x32, acc = 10 x f32x4 per wave.
__global__ __launch_bounds__(512, 4) void gvq_gemm(
    const float* __restrict__ hidden,    // [32768][512] f32
    const float* __restrict__ gumbel_u,  // [65536][320] f32
    const short* __restrict__ wpk,       // fragment-packed bf16
    const float* __restrict__ bias,      // [640]
    const float* __restrict__ cv,        // [640][128]
    float* __restrict__ out,             // [32768][256] + perp scalar
    float* __restrict__ gavg)            // [NSLOT][640]
{
    __shared__ short A_lds[32 * CHUNK];            // 16 ts x 2 rq chunks, 33.3 KB
    __shared__ float s_psum[G_][2][32];
    __shared__ float s_bestv[G_][2][32];
    __shared__ int   s_besti[G_][2][32];

    const int t    = threadIdx.x;
    const int wave = t >> 6;
    const int lane = t & 63;
    const int l15  = lane & 15;
    const int kq   = lane >> 4;
    const int rq   = wave >> 2;          // row half (16 rows)
    const int cq   = wave & 3;
    const int g    = cq >> 1;
    const int ch   = cq & 1;
    const int rb   = blockIdx.x;
    const int m0   = rb * 32;

    // ---- stage A: thread (sr, sc) converts hidden[m0+sr][sc*32..+32] into frag chunks ----
    {
        const int sr = t >> 4, sc = t & 15;
        const float* hsrc = hidden + (size_t)(m0 + sr) * CDIM + sc * 32;
        short* adst = &A_lds[(sc * 2 + (sr >> 4)) * CHUNK + (sr & 15) * 8];
        #pragma unroll
        for (int j = 0; j < 8; ++j) {
            float4 v = *(const float4*)(hsrc + j * 4);
            bf16x4 p;
            p[0] = f2bf(v.x); p[1] = f2bf(v.y); p[2] = f2bf(v.z); p[3] = f2bf(v.w);
            *(bf16x4*)(adst + (j >> 1) * 128 + (j & 1) * 4) = p;   // slot kq=(j>>1), e0=(j&1)*4
        }
    }
    __syncthreads();

    f32x4 acc[10];
    #pragma unroll
    for (int tt = 0; tt < 10; ++tt)
        #pragma unroll
        for (int r = 0; r < 4; ++r) acc[tt][r] = 0.f;

    const short* wbase = wpk + ((size_t)(g * 16) * 20 + ch * 10) * 512 + (size_t)lane * 8;
    const short* abase = A_lds + rq * CHUNK + (size_t)lane * 8;

    // prologue
    bf16x8 a0 = *(const bf16x8*)(abase);
    bf16x8 b0[5];
    #pragma unroll
    for (int j = 0; j < 5; ++j) b0[j] = *(const bf16x8*)(wbase + j * 512);

    #pragma unroll
    for (int ts = 0; ts < 16; ++ts) {
        const short* wts = wbase + ts * 10240;
        bf16x8 b1[5];
        #pragma unroll
        for (int j = 0; j < 5; ++j) b1[j] = *(const bf16x8*)(wts + (5 + j) * 512);
        bf16x8 a1;
        if (ts < 15) a1 = *(const bf16x8*)(abase + (ts + 1) * 2 * CHUNK);
        #pragma unroll
        for (int j = 0; j < 5; ++j)
            acc[j] = __builtin_amdgcn_mfma_f32_16x16x32_bf16(a0, b0[j], acc[j], 0, 0, 0);
        if (ts < 15) {
            #pragma unroll
            for (int j = 0; j < 5; ++j)
                b0[j] = *(const bf16x8*)(wts + 10240 + j * 512);
        }
        #pragma unroll
        for (int j = 0; j < 5; ++j)
            acc[5 + j] = __builtin_amdgcn_mfma_f32_16x16x32_bf16(a0, b1[j], acc[5 + j], 0, 0, 0);
        a0 = a1;
    }

    // ---- epilogue ----
    // C/D: col = g*320 + ch*160 + tt*16 + l15, block row rl = rq*16 + kq*4 + r
    float bvv[10];
    #pragma unroll
    for (int tt = 0; tt < 10; ++tt) bvv[tt] = bias[g * V_ + ch * 160 + tt * 16 + l15];

    {   // exp(z) direct + row sums + 1-log gumbel ratio argmax; u-loads pipelined
        float ub[10], un[10];
        {
            const float* up0 = gumbel_u + ((size_t)(m0 + rq * 16 + kq * 4) * G_ + g) * V_ + ch * 160 + l15;
            #pragma unroll
            for (int tt = 0; tt < 10; ++tt) ub[tt] = up0[tt * 16];
        }
        #pragma unroll
        for (int r = 0; r < 4; ++r) {
            const int rl = rq * 16 + kq * 4 + r;
            if (r < 3) {
                const float* upn = gumbel_u + ((size_t)(m0 + rl + 1) * G_ + g) * V_ + ch * 160 + l15;
                #pragma unroll
                for (int tt = 0; tt < 10; ++tt) un[tt] = upn[tt * 16];
            }
            float s = 0.f, best = -1e30f; int bi = 0;
            #pragma unroll
            for (int tt = 0; tt < 10; ++tt) {
                float z = fminf(acc[tt][r] + bvv[tt], 60.f);
                float e = __expf(z);
                acc[tt][r] = e;                              // keep numerator for cp pass
                s += e;
                float w = -__logf(ub[tt] + 1e-10f) + 1e-10f;
                float ratio = e * __builtin_amdgcn_rcpf(w);  // argmax(z+gumbel) == argmax e/w
                if (ratio > best) { best = ratio; bi = ch * 160 + tt * 16 + l15; }
            }
            #pragma unroll
            for (int o = 1; o <= 8; o <<= 1) {               // 16-lane group reduce
                s += __shfl_xor(s, o);
                float ov = __shfl_xor(best, o);
                int   oi = __shfl_xor(bi, o);
                if (ov > best || (ov == best && oi < bi)) { best = ov; bi = oi; }
            }
            if (l15 == 0) {
                s_psum[g][ch][rl]  = s;
                s_bestv[g][ch][rl] = best;
                s_besti[g][ch][rl] = bi;
            }
            #pragma unroll
            for (int tt = 0; tt < 10; ++tt) ub[tt] = un[tt];
        }
    }
    __syncthreads();

    // probability accumulation -> fold kq groups -> sliced global atomics
    float cp[10];
    #pragma unroll
    for (int tt = 0; tt < 10; ++tt) cp[tt] = 0.f;
    #pragma unroll
    for (int r = 0; r < 4; ++r) {
        const int rl = rq * 16 + kq * 4 + r;
        const float inv = 1.f / (s_psum[g][0][rl] + s_psum[g][1][rl]);
        #pragma unroll
        for (int tt = 0; tt < 10; ++tt) cp[tt] += acc[tt][r] * inv;
    }
    #pragma unroll
    for (int tt = 0; tt < 10; ++tt) {
        cp[tt] += __shfl_xor(cp[tt], 16);
        cp[tt] += __shfl_xor(cp[tt], 32);
    }
    float* gslot = gavg + (size_t)(rb & (NSLOT - 1)) * NCOLS;
    if (kq == 0) {
        #pragma unroll
        for (int tt = 0; tt < 10; ++tt)
            atomicAdd(&gslot[g * V_ + ch * 160 + tt * 16 + l15], cp[tt]);
    }

    // final argmax across col-halves + codevector gather + write: 64 (row,g) tasks / 8 waves
    #pragma unroll
    for (int i = 0; i < 8; ++i) {
        const int id = wave * 8 + i;
        const int R = id >> 1, gg = id & 1;
        float v0 = s_bestv[gg][0][R], v1 = s_bestv[gg][1][R];
        int   i0 = s_besti[gg][0][R], i1 = s_besti[gg][1][R];
        int bidx = (v1 > v0) ? i1 : i0;     // tie -> ch0 (smaller index)
        float2 cvv = *(const float2*)(cv + ((size_t)gg * V_ + bidx) * DCODE + lane * 2);
        *(float2*)(out + (size_t)(m0 + R) * (G_ * DCODE) + gg * DCODE + lane * 2) = cvv;
    }
}

__global__ __launch_bounds__(64) void gvq_perp(const float* __restrict__ gavg,
                                               float* __restrict__ out, int nslot)
{
    const int lane = threadIdx.x;
    float s0 = 0.f, s1 = 0.f;
    for (int v = lane; v < V_; v += 64) {
        float p0 = 0.f, p1 = 0.f;
        for (int s = 0; s < nslot; ++s) {
            p0 += gavg[(size_t)s * NCOLS + v];
            p1 += gavg[(size_t)s * NCOLS + V_ + v];
        }
        p0 *= (1.f / NROWS); p1 *= (1.f / NROWS);
        s0 += p0 * logf(p0 + 1e-7f);
        s1 += p1 * logf(p1 + 1e-7f);
    }
    #pragma unroll
    for (int o = 32; o >= 1; o >>= 1) {
        s0 += __shfl_xor(s0, o);
        s1 += __shfl_xor(s1, o);
    }
    if (lane == 0)
        out[(size_t)NROWS * (G_ * DCODE)] = expf(-s0) + expf(-s1);
}

extern "C" void kernel_launch(void* const* d_in, const int* in_sizes, int n_in,
                              void* d_out, int out_size, void* d_ws, size_t ws_size,
                              hipStream_t stream)
{
    const float* hidden = (const float*)d_in[0];
    const float* gu     = (const float*)d_in[1];
    const float* w      = (const float*)d_in[2];
    const float* b      = (const float*)d_in[3];
    const float* cv     = (const float*)d_in[4];
    float* out  = (float*)d_out;
    float* gavg = (float*)d_ws;                       // [NSLOT][640] f32 = 80 KB
    short* wpk  = (short*)((char*)d_ws + 81920);      // 640 KB fragment-packed W

    hipMemsetAsync(d_ws, 0, NSLOT * NCOLS * sizeof(float), stream);
    wprep<<<160, 256, 0, stream>>>(w, wpk);
    gvq_gemm<<<NROWS / 32, 512, 0, stream>>>(hidden, gu, wpk, b, cv, out, gavg);
    gvq_perp<<<1, 64, 0, stream>>>(gavg, out, NSLOT);
}